// Round 11
// baseline (312.235 us; speedup 1.0000x reference)
//
#include <hip/hip_runtime.h>

#define T_LEN 1024
#define P_DIM 32
#define HOME_IDX 0
#define NCHUNK 32
#define CHUNK 32

// One wave (lanes 0-63) per batch; 1024 threads/block exist only for the
// parallel chunked backtrack (waves 1-15 sleep at the post-loop barrier).
//
// Base = round-10 PROVEN kernel (245 us rocprof; best verified): LDS-restage
// delta broadcast (1 ds_write_b32 + 4 uniform-address ds_read_b128, in-order
// DS pipe, no barrier) + r4's lean 16-q-per-half VALU budget.
//
// THIS round's single change — fuse the step's two serialized DS round trips
// into one. r10's chain had: shfl(bv) RT -> scan vs v1 -> shfl(ia) RT (the
// end-of-step min stalls on it). Now:
//   * scan the argmax against the LOCAL bv BEFORE any shuffle (bv always
//     equals some c[j], so the scan is well-defined);
//   * issue shfl_xor(bv,32) and shfl_xor(ia,32) BACK-TO-BACK -> their
//     latencies overlap in the in-order DS pipe (one RT window, not two);
//   * exact first-index combine in 4 VALU ops:
//       a1 = (bv > ovv) ? ia : (ovv > bv) ? oia : min(ia, oia)
//     tie -> min = half 0's index (owns q in [0,16)) => reference semantics.
//   * psi write stays UNCONDITIONAL, both halves, identical bytes (symmetric
//     inputs -> same a1 in both lanes of the pair; r9's divergent
//     winner-write is NOT repeated — it regressed).
//
// Exactness notes (harness-verified across rounds):
//  * NEG = finfo(f32).min/4; ulp(NEG) >> |A|<=0.01, so NEG + A == NEG; the
//    v=0 slice is NEG except q=HOME -> v0[p] = delta0h + A[0][p], a0 = 0.
//  * use1 = (v1 > v0) strict, matching the reference.
//  * local argmax scan: c[j]==bv, descending-j, init j=15 -> FIRST matching
//    local index (fmax returns an input bit-exactly; +-0 compare equal;
//    inputs NaN-free).
//  * delta0h update order preserved: (delta0h + A00) + (u[t,0] + bias0).
//
// Backtrack (PROVEN in round 4): 1023 backsteps in 32 chunks of <=32.
// Phase 1: 1024 threads build per-chunk (y,v)-maps for all 32 v=1 entry
// states. Phase 2: one thread composes maps from (last_p,1); v=0 absorbing
// at (0,0). Phase 3: 32 lanes re-walk their chunk from its true entry.
// Per-backstep rule identical to serial: if v: (y,v)=(byte&31,(byte>>5)&1)
// else (0,0); out[i] = new y.

__launch_bounds__(1024, 1)
__global__ void crf_viterbi_kernel(const float* __restrict__ U,
                                   const float* __restrict__ A,
                                   const float* __restrict__ bias,
                                   int* __restrict__ out)
{
    __shared__ __align__(16) float sdelta[P_DIM];         // 128 B delta stage
    __shared__ unsigned char spsi[(T_LEN - 1) * P_DIM];   // 32736 B
    __shared__ unsigned char Mmap[NCHUNK * P_DIM];        // chunk maps
    __shared__ unsigned char ent[NCHUNK];                 // chunk entry states
    __shared__ int last_p_sh;

    const int tid = threadIdx.x;
    const int b   = blockIdx.x;
    int* __restrict__ outb = out + (size_t)b * T_LEN;

    if (tid < 64) {
        const int lane = tid;
        const int p    = lane & 31;
        const int h    = lane >> 5;
        const float NEG = -(3.4028234663852886e38f / 4.0f);

        // A fragment: A[q][p] for q = 16*h + j
        float Areg[16];
#pragma unroll
        for (int j = 0; j < 16; ++j)
            Areg[j] = A[(16 * h + j) * P_DIM + p];
        const float A0p    = A[p];        // A[HOME][p]
        const float A00    = A[0];        // A[HOME][HOME]
        const float bias_p = bias[p];
        const float bias0  = bias[0];
        const int   q0     = h << 4;      // first q of this half
        const bool  is_home = (p == HOME_IDX);

        const float4* __restrict__ sd4 = (const float4*)sdelta;

        const float* __restrict__ Ub = U + (size_t)b * T_LEN * P_DIM;

        // t = 0 init
        const float u00 = Ub[p] + bias_p;
        float delta1  = is_home ? NEG : u00;     // v=1 slice, per-lane p
        float delta0h = Ub[HOME_IDX] + bias0;    // v=0 slice at HOME (uniform)

        // Prefetch ring, depth 4. Row t lives in slot (t-1)&3.
        float L0 = Ub[1 * P_DIM + p];
        float L1 = Ub[2 * P_DIM + p];
        float L2 = Ub[3 * P_DIM + p];
        float L3 = Ub[4 * P_DIM + p];

        float Ut_n = L0 + bias_p;          // for t = 1
        float u0_n = __shfl(Ut_n, 0);      // u[t,0] + bias0, broadcast

        // Stage initial delta; read this half's 16 q's (in-order DS pipe).
        sdelta[p] = delta1;
        float4 R0 = sd4[4 * h + 0];
        float4 R1 = sd4[4 * h + 1];
        float4 R2 = sd4[4 * h + 2];
        float4 R3 = sd4[4 * h + 3];

#define STEP(t, Lc, Lr) do {                                                   \
    const float Ut  = Ut_n;                                                    \
    const float u0c = u0_n;                                                    \
    Ut_n = (Lc) + bias_p;                                                      \
    u0_n = __shfl(Ut_n, 0);                                                    \
    { int tn = (t) + 4; if (tn > T_LEN - 1) tn = T_LEN - 1;                    \
      (Lr) = Ub[(size_t)tn * P_DIM + p]; }                                     \
    float c[16];                                                               \
    c[0]  = R0.x + Areg[0];  c[1]  = R0.y + Areg[1];                           \
    c[2]  = R0.z + Areg[2];  c[3]  = R0.w + Areg[3];                           \
    c[4]  = R1.x + Areg[4];  c[5]  = R1.y + Areg[5];                           \
    c[6]  = R1.z + Areg[6];  c[7]  = R1.w + Areg[7];                           \
    c[8]  = R2.x + Areg[8];  c[9]  = R2.y + Areg[9];                           \
    c[10] = R2.z + Areg[10]; c[11] = R2.w + Areg[11];                          \
    c[12] = R3.x + Areg[12]; c[13] = R3.y + Areg[13];                          \
    c[14] = R3.z + Areg[14]; c[15] = R3.w + Areg[15];                          \
    /* value-only max tree over this half's 16 (v_max3-friendly, depth 3) */   \
    const float g0 = fmaxf(fmaxf(c[0],  c[1]),  c[2]);                         \
    const float g1 = fmaxf(fmaxf(c[3],  c[4]),  c[5]);                         \
    const float g2 = fmaxf(fmaxf(c[6],  c[7]),  c[8]);                         \
    const float g3 = fmaxf(fmaxf(c[9],  c[10]), c[11]);                        \
    const float g4 = fmaxf(fmaxf(c[12], c[13]), c[14]);                        \
    const float h0 = fmaxf(fmaxf(g0, g1), g2);                                 \
    const float h1 = fmaxf(fmaxf(g3, g4), c[15]);                              \
    const float bv = fmaxf(h0, h1);                                            \
    /* local argmax vs LOCAL bv (before any shuffle): first matching j */      \
    int ia = q0 + 15;                                                          \
    _Pragma("unroll")                                                          \
    for (int j = 14; j >= 0; --j)                                              \
        if (c[j] == bv) ia = q0 + j;                                           \
    /* both cross-half exchanges back-to-back: ONE overlapped RT window */     \
    const float ovv = __shfl_xor(bv, 32);                                      \
    const int   oia = __shfl_xor(ia, 32);                                      \
    const float v1  = fmaxf(bv, ovv);                                          \
    const float v0  = delta0h + A0p;                                           \
    const bool  use1 = (v1 > v0);              /* strict, as reference */      \
    const bool  cond = use1 || is_home;                                        \
    const float sel  = cond ? v1 : v0;                                         \
    const float dn1  = sel + Ut;                                               \
    delta0h = (delta0h + A00) + u0c;                                           \
    /* exact first-index combine (tie -> min = half 0's index) */              \
    const int amin = (ia < oia) ? ia : oia;                                    \
    int a1 = (bv > ovv) ? ia : oia;                                            \
    a1 = (bv == ovv) ? amin : a1;                                              \
    const int bt = cond ? (a1 | 32) : 0;                                       \
    /* restage delta + issue next step's reads (in-order DS, no barrier) */    \
    sdelta[p] = dn1;                                                           \
    R0 = sd4[4 * h + 0];                                                       \
    R1 = sd4[4 * h + 1];                                                       \
    R2 = sd4[4 * h + 2];                                                       \
    R3 = sd4[4 * h + 3];                                                       \
    spsi[(size_t)((t) - 1) * P_DIM + p] = (unsigned char)bt;                   \
    delta1 = dn1;                                                              \
} while (0)

        STEP(1, L1, L0);
        STEP(2, L2, L1);
        STEP(3, L3, L2);
        for (int t = 4; t <= T_LEN - 4; t += 4) {
            STEP(t + 0, L0, L3);
            STEP(t + 1, L1, L0);
            STEP(t + 2, L2, L1);
            STEP(t + 3, L3, L2);
        }
#undef STEP

        // last_p = argmax_p delta_T[:,1], first index wins (lexicographic
        // butterfly; lanes 32..63 duplicate p = lane-32, idx tie-break wins).
        float mv = delta1;
        int   mi = p;
#pragma unroll
        for (int m = 16; m >= 1; m >>= 1) {
            float ov = __shfl_xor(mv, m);
            int   oi = __shfl_xor(mi, m);
            bool take = (ov > mv) || ((ov == mv) && (oi < mi));
            mv = take ? ov : mv;
            mi = take ? oi : mi;
        }
        if (lane == 0) {
            outb[T_LEN - 1] = mi;
            last_p_sh = mi;
        }
    }

    __syncthreads();   // psi + last_p visible to all 16 waves

    // Phase 1: per-chunk maps. Chunk c covers backsteps i in
    // [32c, min(32c+32, 1023)). Thread (c = tid>>5, pp = tid&31) walks from
    // hypothetical entry (pp, v=1).
    {
        const int c  = tid >> 5;
        const int pp = tid & 31;
        const int i_hi = min((c + 1) * CHUNK, T_LEN - 1);
        const int i_lo = c * CHUNK;
        int y = pp, v = 1;
        for (int i = i_hi - 1; i >= i_lo; --i) {
            const int bt = spsi[i * P_DIM + y];
            const int py = v ? (bt & 31) : 0;
            const int nv = v ? ((bt >> 5) & 1) : 0;
            y = py; v = nv;
        }
        Mmap[c * P_DIM + pp] = (unsigned char)(y | (v << 5));
    }
    __syncthreads();

    // Phase 2: compose maps from the top to get each chunk's true entry state.
    if (tid == 0) {
        int y = last_p_sh, v = 1;
        for (int c = NCHUNK - 1; c >= 0; --c) {
            ent[c] = (unsigned char)(y | (v << 5));
            if (v) {
                const int m = Mmap[c * P_DIM + y];
                y = m & 31;
                v = (m >> 5) & 1;
            } else {
                y = 0; v = 0;
            }
        }
    }
    __syncthreads();

    // Phase 3: 32 lanes re-walk their chunk from the true entry, emitting out.
    if (tid < NCHUNK) {
        const int c = tid;
        const int i_hi = min((c + 1) * CHUNK, T_LEN - 1);
        const int i_lo = c * CHUNK;
        const int e = ent[c];
        int y = e & 31;
        int v = (e >> 5) & 1;
        for (int i = i_hi - 1; i >= i_lo; --i) {
            const int bt = spsi[i * P_DIM + y];
            const int py = v ? (bt & 31) : 0;
            const int nv = v ? ((bt >> 5) & 1) : 0;
            outb[i] = py;
            y = py; v = nv;
        }
    }
}

extern "C" void kernel_launch(void* const* d_in, const int* in_sizes, int n_in,
                              void* d_out, int out_size, void* d_ws, size_t ws_size,
                              hipStream_t stream) {
    const float* U    = (const float*)d_in[0];   // (B, T, P) f32
    const float* A    = (const float*)d_in[1];   // (P, P)    f32
    const float* bias = (const float*)d_in[2];   // (P,)      f32
    int* out = (int*)d_out;                      // (B, T)    int32

    const int B = in_sizes[0] / (T_LEN * P_DIM);
    crf_viterbi_kernel<<<B, 1024, 0, stream>>>(U, A, bias, out);
}